// Round 4
// baseline (49.431 us; speedup 1.0000x reference)
//
#include <hip/hip_runtime.h>
#include <math.h>

typedef float  f32x4  __attribute__((ext_vector_type(4)));
typedef short  bf16x8 __attribute__((ext_vector_type(8)));

#define NG  512
#define EPG 2048

__device__ __forceinline__ unsigned short f2bf(float f) {
    union { float f; unsigned u; } v; v.f = f;
    unsigned r = v.u + 0x7fffu + ((v.u >> 16) & 1u);   // RNE
    return (unsigned short)(r >> 16);
}
__device__ __forceinline__ float bf2f(unsigned short h) {
    union { unsigned u; float f; } v; v.u = ((unsigned)h) << 16;
    return v.f;
}
__device__ __forceinline__ bf16x8 ubf(uint4 u) {
    union { uint4 a; bf16x8 b; } c; c.a = u; return c.b;
}

// ---------------------------------------------------------------------------
// wpack: W[t3][fin][fout] f32 -> bf16 MFMA B-fragments (verified round 2/3).
// frag(t3,kt,nt), slot(lane,j) = W[t3][kt*32+lg*8+j][nt*16+li]
// ---------------------------------------------------------------------------
__global__ __launch_bounds__(64) void wpack(
    const float* __restrict__ W1, const float* __restrict__ W2,
    const float* __restrict__ W3, uint4* __restrict__ Wp)
{
    int b = blockIdx.x, lane = threadIdx.x;
    const float* W; int FIN, FOUT, rel, off;
    if (b < 48)       { W = W1; FIN = 64;  FOUT = 128; rel = b;       off = 0;   }
    else if (b < 144) { W = W2; FIN = 128; FOUT = 128; rel = b - 48;  off = 48;  }
    else              { W = W3; FIN = 128; FOUT = 64;  rel = b - 144; off = 144; }
    int NKT = FIN / 32, NNT = FOUT / 16;
    int t3 = rel / (NKT * NNT), r2 = rel % (NKT * NNT);
    int kt = r2 / NNT, nt = r2 % NNT;
    int lg = lane >> 4, li = lane & 15;
    int fin0 = kt*32 + lg*8, fout = nt*16 + li;
    unsigned v[4];
#pragma unroll
    for (int jp = 0; jp < 4; ++jp) {
        unsigned lo = f2bf(W[((size_t)t3*FIN + fin0 + 2*jp    ) * FOUT + fout]);
        unsigned hi = f2bf(W[((size_t)t3*FIN + fin0 + 2*jp + 1) * FOUT + fout]);
        v[jp] = lo | (hi << 16);
    }
    Wp[(size_t)(off + rel)*64 + lane] = make_uint4(v[0],v[1],v[2],v[3]);
}

// ---------------------------------------------------------------------------
// One ChebConv layer, 8 waves, all LDS.
//   H  : node-major [64][128] bf16, stride 256B, swz byte^=((node&7)<<4)
//   Ht : feat-major [128][64] bf16, stride 128B, swz byte^=((feat&7)<<4)
//   per chunk c: Tf[c] (T~1 feat-major, later ALIASED as Tn2) and Tn1[c],
//   both [64][64] bf16 stride 128B.
// NCH==2: waves 0-3 chunk0, 4-7 chunk1 (props in parallel).
// NCH==1: all waves chunk0; wave w does m-tile w&3, nt-half w>>2.
// ---------------------------------------------------------------------------
template <int FIN, int FOUT, bool RELU, bool WT>
__device__ __forceinline__ void layer(
    char* smem, const uint4 (&afr)[2][4], const uint4* __restrict__ Wp,
    const float* __restrict__ bias, int w, int lg, int li, int lane)
{
    constexpr int NCH = FIN / 64;
    constexpr int NKT = FIN / 32;
    constexpr int NNT = FOUT / 16;
    constexpr int M2N = (FOUT == 128) ? 4 : 2;

    unsigned short* H  = (unsigned short*)smem;
    unsigned short* Ht = (unsigned short*)(smem + 16384);
    char* Tf[2]  = { smem + 32768, smem + 49152 };   // T~1, later Tn2 (aliased)
    char* Tn1[2] = { smem + 40960, smem + 57344 };

    const int ch   = (NCH == 2) ? (w >> 2) : 0;
    const int mt   = w & 3;
    const int fcol = mt*16 + lg*4;

    // ---------------- prop1: T~1 = T~0 @ L^T  (A rows from Ht)
    {
        const int frow = ch*64 + mt*16 + li;
        const int fsw  = (frow & 7) << 4;
        bf16x8 a0[2];
#pragma unroll
        for (int kt = 0; kt < 2; ++kt)
            a0[kt] = *(const bf16x8*)((const char*)Ht + frow*128 + ((kt*64 + lg*16) ^ fsw));
#pragma unroll
        for (int nt = 0; nt < 4; ++nt) {
            if (NCH == 1 && (nt >> 1) != (w >> 2)) continue;   // wave-uniform
            f32x4 p = {0.f,0.f,0.f,0.f};
            p = __builtin_amdgcn_mfma_f32_16x16x32_bf16(a0[0], ubf(afr[0][nt]), p, 0,0,0);
            p = __builtin_amdgcn_mfma_f32_16x16x32_bf16(a0[1], ubf(afr[1][nt]), p, 0,0,0);
            unsigned short q0 = f2bf(p[0]), q1 = f2bf(p[1]);
            unsigned short q2 = f2bf(p[2]), q3 = f2bf(p[3]);
            const int nrow = nt*16 + li;
            *(uint2*)(Tn1[ch] + nrow*128 + ((fcol*2) ^ ((nrow&7)<<4))) =
                make_uint2(q0 | ((unsigned)q1<<16), q2 | ((unsigned)q3<<16));
            *(unsigned short*)(Tf[ch] + (fcol+0)*128 + ((nrow*2) ^ (((fcol+0)&7)<<4))) = q0;
            *(unsigned short*)(Tf[ch] + (fcol+1)*128 + ((nrow*2) ^ (((fcol+1)&7)<<4))) = q1;
            *(unsigned short*)(Tf[ch] + (fcol+2)*128 + ((nrow*2) ^ (((fcol+2)&7)<<4))) = q2;
            *(unsigned short*)(Tf[ch] + (fcol+3)*128 + ((nrow*2) ^ (((fcol+3)&7)<<4))) = q3;
        }
    }
    __syncthreads();   // T~1 complete

    // ---------------- load prop2 A-fragments (before Tn2 aliases Tf!)
    bf16x8 a1[2];
    {
        const int frow = mt*16 + li;
        const int fsw  = (frow & 7) << 4;
#pragma unroll
        for (int kt = 0; kt < 2; ++kt)
            a1[kt] = *(const bf16x8*)(Tf[ch] + frow*128 + ((kt*64 + lg*16) ^ fsw));
    }
    __syncthreads();   // all waves hold a1 in regs; Tf now reusable as Tn2

    // ---------------- prop2: T2 = 2*(T~1 @ L^T) - T0 -> Tn2 (= Tf alias)
    {
#pragma unroll
        for (int nt = 0; nt < 4; ++nt) {
            if (NCH == 1 && (nt >> 1) != (w >> 2)) continue;
            f32x4 p = {0.f,0.f,0.f,0.f};
            p = __builtin_amdgcn_mfma_f32_16x16x32_bf16(a1[0], ubf(afr[0][nt]), p, 0,0,0);
            p = __builtin_amdgcn_mfma_f32_16x16x32_bf16(a1[1], ubf(afr[1][nt]), p, 0,0,0);
            const int nrow = nt*16 + li;
            uint2 t0p = *(const uint2*)((const char*)H + nrow*256 +
                                        (((ch*64 + fcol)*2) ^ ((nrow&7)<<4)));
            float t00 = bf2f((unsigned short)(t0p.x & 0xffff));
            float t01 = bf2f((unsigned short)(t0p.x >> 16));
            float t02 = bf2f((unsigned short)(t0p.y & 0xffff));
            float t03 = bf2f((unsigned short)(t0p.y >> 16));
            unsigned short q0 = f2bf(2.f*p[0] - t00), q1 = f2bf(2.f*p[1] - t01);
            unsigned short q2 = f2bf(2.f*p[2] - t02), q3 = f2bf(2.f*p[3] - t03);
            *(uint2*)(Tf[ch] + nrow*128 + ((fcol*2) ^ ((nrow&7)<<4))) =
                make_uint2(q0 | ((unsigned)q1<<16), q2 | ((unsigned)q3<<16));
        }
    }
    __syncthreads();   // T1/T2 node-major complete

    // ---------------- weight MFMAs: out = sum_t3 T_t3 @ W_t3 (full K)
    const int ntg = (FOUT == 128) ? w : (w & 3);
    const int m2b = (FOUT == 128) ? 0 : ((w >> 2) * 2);
    f32x4 oacc[M2N];
#pragma unroll
    for (int m = 0; m < M2N; ++m) oacc[m] = (f32x4){0.f,0.f,0.f,0.f};

#pragma unroll
    for (int t3 = 0; t3 < 3; ++t3) {
        uint4 wf[NKT];
#pragma unroll
        for (int k = 0; k < NKT; ++k)
            wf[k] = Wp[((size_t)(t3*NKT + k)*NNT + ntg)*64 + lane];
#pragma unroll
        for (int k = 0; k < NKT; ++k) {
            const int cc = k >> 1, kk = k & 1;
#pragma unroll
            for (int m = 0; m < M2N; ++m) {
                const int rr = (m2b + m)*16 + li;
                const int sw = (rr & 7) << 4;
                bf16x8 ta;
                if (t3 == 0)
                    ta = *(const bf16x8*)((const char*)H + rr*256 + ((k*64 + lg*16) ^ sw));
                else if (t3 == 1)
                    ta = *(const bf16x8*)(Tn1[cc] + rr*128 + ((kk*64 + lg*16) ^ sw));
                else
                    ta = *(const bf16x8*)(Tf[cc]  + rr*128 + ((kk*64 + lg*16) ^ sw));
                oacc[m] = __builtin_amdgcn_mfma_f32_16x16x32_bf16(ta, ubf(wf[k]), oacc[m], 0,0,0);
            }
        }
    }
    __syncthreads();   // weight reads of H/Ht done -> safe to overwrite

    // ---------------- epilogue: bias (+ReLU) -> H (+Ht)
    {
        const int fout = ntg*16 + li;
        const float bv = bias[fout];
#pragma unroll
        for (int m = 0; m < M2N; ++m) {
            f32x4 v = oacc[m];
            unsigned short q[4];
#pragma unroll
            for (int r = 0; r < 4; ++r) {
                float o = v[r] + bv;
                if (RELU) o = fmaxf(o, 0.f);
                q[r] = f2bf(o);
            }
            const int node0 = (m2b + m)*16 + lg*4;
#pragma unroll
            for (int r = 0; r < 4; ++r)
                *(unsigned short*)((char*)H + (node0+r)*256 +
                                   ((fout*2) ^ (((node0+r)&7)<<4))) = q[r];
            if (WT)
                *(uint2*)((char*)Ht + fout*128 + ((node0*2) ^ ((fout&7)<<4))) =
                    make_uint2(q[0] | ((unsigned)q[1]<<16), q[2] | ((unsigned)q[3]<<16));
        }
    }
    __syncthreads();   // next phase reads H/Ht
}

// ---------------------------------------------------------------------------
// fused: build L_hat -> 3 ChebConv layers -> meanmax readout + FC.
// One block (512 threads, 8 waves) per graph; 64KB LDS -> 2 blocks/CU.
// ---------------------------------------------------------------------------
__global__ __launch_bounds__(512, 4) void fused(
    const float* __restrict__ X,  const float* __restrict__ ew,
    const int* __restrict__ row,  const int* __restrict__ col,
    const uint4* __restrict__ Wp,
    const float* __restrict__ b1, const float* __restrict__ b2,
    const float* __restrict__ b3,
    const float* __restrict__ fcw, const float* __restrict__ fcb,
    float* __restrict__ outp)
{
    __shared__ __align__(16) char smem[65536];
    unsigned short* H  = (unsigned short*)smem;
    unsigned short* Ht = (unsigned short*)(smem + 16384);
    float* sA    = (float*)(smem + 32768);   // 16KB, aliases Tf[0]+Tn1[0]
    float* sdinv = (float*)(smem + 49152);   // aliases Tf[1]

    const int g = blockIdx.x, t = threadIdx.x;
    const int w = t >> 6, lane = t & 63, lg = lane >> 4, li = lane & 15;

    // ---- phase 0: scatter raw ew into dense sA  (sA[r*64+c], edge row=r,col=c)
    for (int i = t; i < 4096; i += 512) sA[i] = 0.f;
    __syncthreads();
    const int e0 = g * EPG;
    for (int e = t; e < EPG; e += 512)
        atomicAdd(&sA[(row[e0+e] & 63)*64 + (col[e0+e] & 63)], ew[e0+e]);
    __syncthreads();

    // ---- deg = row-sum; dinv = rsqrt
    {
        const int r = t >> 3, s8 = (t & 7) * 8;
        float p = 0.f;
#pragma unroll
        for (int j = 0; j < 8; ++j) p += sA[r*64 + s8 + j];
        p += __shfl_xor(p, 1); p += __shfl_xor(p, 2); p += __shfl_xor(p, 4);
        if ((t & 7) == 0) sdinv[r] = (p > 0.f) ? rsqrtf(p) : 0.f;
    }
    __syncthreads();

    // ---- normalize in place: sA[r][c] = -dinv[r]*ew_sum*dinv[c]
    for (int i = t; i < 4096; i += 512) {
        const int r = i >> 6, c = i & 63;
        sA[i] = -sA[i] * sdinv[r] * sdinv[c];
    }
    __syncthreads();

    // ---- pack L^T B-fragments into regs: afr[kt][nt](lane,j)=L_hat[n][k]=sA[k*64+n]
    uint4 afr[2][4];
#pragma unroll
    for (int kt = 0; kt < 2; ++kt)
#pragma unroll
        for (int nt = 0; nt < 4; ++nt) {
            const int k0 = kt*32 + lg*8, n = nt*16 + li;
            unsigned v[4];
#pragma unroll
            for (int jp = 0; jp < 4; ++jp) {
                unsigned lo = f2bf(sA[(k0 + 2*jp    )*64 + n]);
                unsigned hi = f2bf(sA[(k0 + 2*jp + 1)*64 + n]);
                v[jp] = lo | (hi << 16);
            }
            afr[kt][nt] = make_uint4(v[0], v[1], v[2], v[3]);
        }

    // ---- stage x into H / Ht as bf16 (disjoint from sA region)
    const float4* xg = (const float4*)(X + (size_t)g * 4096);
    for (int i = t; i < 1024; i += 512) {
        const int node = i >> 4, f0 = (i & 15) * 4;
        float4 v = xg[i];
        unsigned short h0 = f2bf(v.x), h1 = f2bf(v.y);
        unsigned short h2 = f2bf(v.z), h3 = f2bf(v.w);
        *(uint2*)((char*)H + node*256 + ((f0*2) ^ ((node&7)<<4))) =
            make_uint2(h0 | ((unsigned)h1<<16), h2 | ((unsigned)h3<<16));
        *(unsigned short*)((char*)Ht + (f0+0)*128 + ((node*2) ^ (((f0+0)&7)<<4))) = h0;
        *(unsigned short*)((char*)Ht + (f0+1)*128 + ((node*2) ^ (((f0+1)&7)<<4))) = h1;
        *(unsigned short*)((char*)Ht + (f0+2)*128 + ((node*2) ^ (((f0+2)&7)<<4))) = h2;
        *(unsigned short*)((char*)Ht + (f0+3)*128 + ((node*2) ^ (((f0+3)&7)<<4))) = h3;
    }
    __syncthreads();   // afr packed + x staged

    layer<64, 128, true,  true >(smem, afr, Wp,                  b1, w, lg, li, lane);
    layer<128, 128, true, true >(smem, afr, Wp + (size_t)48*64,  b2, w, lg, li, lane);
    layer<128, 64, false, false>(smem, afr, Wp + (size_t)144*64, b3, w, lg, li, lane);

    // ---- readout: meanmax over nodes + FC (H = [64 nodes][64 feats])
    float* rm    = (float*)(smem + 32768);   // [8][64]
    float* rx    = rm + 512;                 // [8][64]
    float* smean = rx + 512;                 // [64]
    float* smax  = smean + 64;               // [64]
    float* part  = smax + 64;                // [128]
    const int f = t & 63, q = t >> 6;
    {
        float sum = 0.f, mx = -INFINITY;
        for (int n = q*8; n < q*8 + 8; ++n) {
            float v = bf2f(*(const unsigned short*)((const char*)H + n*256 +
                                                    ((f*2) ^ ((n&7)<<4))));
            sum += v; mx = fmaxf(mx, v);
        }
        rm[q*64 + f] = sum; rx[q*64 + f] = mx;
    }
    __syncthreads();
    if (t < 64) {
        float s = 0.f, m = -INFINITY;
#pragma unroll
        for (int qq = 0; qq < 8; ++qq) {
            s += rm[qq*64 + t];
            m = fmaxf(m, rx[qq*64 + t]);
        }
        smean[t] = s * (1.f/64.f);
        smax[t]  = m;
    }
    __syncthreads();
    if (t < 128) {
        const int j = t & 63, h = t >> 6;
        const float* wv = fcw + (size_t)h*64*64;
        const float* sv = h ? smax : smean;
        float acc = 0.f;
        for (int f2 = 0; f2 < 64; ++f2) acc += sv[f2] * wv[f2*64 + j];
        part[t] = acc;
    }
    __syncthreads();
    if (t < 64) outp[(size_t)g*64 + t] = part[t] + part[64 + t] + fcb[t];
}

// ---------------------------------------------------------------------------
extern "C" void kernel_launch(void* const* d_in, const int* in_sizes, int n_in,
                              void* d_out, int out_size, void* d_ws, size_t ws_size,
                              hipStream_t stream)
{
    const float* x   = (const float*)d_in[0];
    const float* ew  = (const float*)d_in[1];
    const float* W1  = (const float*)d_in[2];
    const float* b1  = (const float*)d_in[3];
    const float* W2  = (const float*)d_in[4];
    const float* b2  = (const float*)d_in[5];
    const float* W3  = (const float*)d_in[6];
    const float* b3  = (const float*)d_in[7];
    const float* fcw = (const float*)d_in[8];
    const float* fcb = (const float*)d_in[9];
    const int*   row = (const int*)d_in[10];
    const int*   col = (const int*)d_in[11];

    uint4* Wp = (uint4*)d_ws;   // 192 frags * 64 lanes * 16B = 192KB

    wpack<<<192, 64, 0, stream>>>(W1, W2, W3, Wp);
    fused<<<NG, 512, 0, stream>>>(x, ew, row, col, Wp,
                                  b1, b2, b3, fcw, fcb, (float*)d_out);
}

// Round 5
// 36.716 us; speedup vs baseline: 1.3463x; 1.3463x over previous
//
#include <hip/hip_runtime.h>
#include <math.h>

typedef float  f32x4  __attribute__((ext_vector_type(4)));
typedef short  bf16x8 __attribute__((ext_vector_type(8)));

#define NG  512
#define EPG 2048

// ---- LDS layout (80KB -> 2 blocks/CU) ----
#define H_OFF    0        // [64][FOUT] node-major (L1 in: [64][64] 128B; else 256B)
#define HT_OFF   16384    // [FIN][64] feat-major, 128B rows
#define TN1_OFF  32768    // T1 node-major (phase0: aliases sA f32 64x64)
#define TN2_OFF  49152    // T2 node-major (phase0: aliases sdinv)
#define LN_OFF   65536    // L^T stored [n][k] bf16 64x64, 128B rows (readout: pS/pM)
#define L2N_OFF  73728    // (2L^2-I)^T stored [n][k]            (readout: smean/smax/part)
#define LDS_SZ   81920

__device__ __forceinline__ unsigned short f2bf(float f) {
    union { float f; unsigned u; } v; v.f = f;
    unsigned r = v.u + 0x7fffu + ((v.u >> 16) & 1u);   // RNE
    return (unsigned short)(r >> 16);
}
__device__ __forceinline__ bf16x8 ubf(uint4 u) {
    union { uint4 a; bf16x8 b; } c; c.a = u; return c.b;
}

// ---------------------------------------------------------------------------
// wpack: W[t3][fin][fout] f32 -> bf16 MFMA B-fragments (verified r2-r4).
// frag(t3,kt,nt), slot(lane,j) = W[t3][kt*32+lg*8+j][nt*16+li]
// ---------------------------------------------------------------------------
__global__ __launch_bounds__(64) void wpack(
    const float* __restrict__ W1, const float* __restrict__ W2,
    const float* __restrict__ W3, uint4* __restrict__ Wp)
{
    int b = blockIdx.x, lane = threadIdx.x;
    const float* W; int FIN, FOUT, rel, off;
    if (b < 48)       { W = W1; FIN = 64;  FOUT = 128; rel = b;       off = 0;   }
    else if (b < 144) { W = W2; FIN = 128; FOUT = 128; rel = b - 48;  off = 48;  }
    else              { W = W3; FIN = 128; FOUT = 64;  rel = b - 144; off = 144; }
    int NKT = FIN / 32, NNT = FOUT / 16;
    int t3 = rel / (NKT * NNT), r2 = rel % (NKT * NNT);
    int kt = r2 / NNT, nt = r2 % NNT;
    int lg = lane >> 4, li = lane & 15;
    int fin0 = kt*32 + lg*8, fout = nt*16 + li;
    unsigned v[4];
#pragma unroll
    for (int jp = 0; jp < 4; ++jp) {
        unsigned lo = f2bf(W[((size_t)t3*FIN + fin0 + 2*jp    ) * FOUT + fout]);
        unsigned hi = f2bf(W[((size_t)t3*FIN + fin0 + 2*jp + 1) * FOUT + fout]);
        v[jp] = lo | (hi << 16);
    }
    Wp[(size_t)(off + rel)*64 + lane] = make_uint4(v[0],v[1],v[2],v[3]);
}

// ---------------------------------------------------------------------------
// One ChebConv layer: prop (T1=T0@L^T, T2=T0@L2^T, same A-frags) | bar |
// weight (wave owns node-tile x fout-half) | bar | epilogue | bar.
// ---------------------------------------------------------------------------
template <int FIN, int FOUT, bool RELU, bool LAST>
__device__ __forceinline__ void layer(
    char* smem, const uint4* __restrict__ Wp, const float* __restrict__ bias,
    int w, int lg, int li, int lane)
{
    constexpr int NKT = FIN / 32;
    constexpr int NNT = FOUT / 16;
    constexpr int NFO = FOUT / 32;            // fo-tiles per wave
    constexpr int TST = (FIN == 128) ? 256 : 128;   // T row stride (H, Tn1, Tn2)
    constexpr int TSM = (FIN == 128) ? 15 : 7;
    constexpr int NTN = (FIN == 128) ? 4 : 2;       // nt tiles per wave in prop

    char* H   = smem + H_OFF;
    char* Ht  = smem + HT_OFF;
    char* Tn1 = smem + TN1_OFF;
    char* Tn2 = smem + TN2_OFF;

    // ---------------- prop: T1 and T2 from the same T0~ A-fragments
    {
        const int mt  = (FIN == 128) ? w : (w & 3);
        const int nt0 = (FIN == 128) ? 0 : ((w >> 2) * 2);
        const int frow = mt*16 + li;
        const int fsw  = (frow & 7) << 4;
        bf16x8 a0[2];
#pragma unroll
        for (int kt = 0; kt < 2; ++kt)
            a0[kt] = *(const bf16x8*)(Ht + frow*128 + ((kt*64 + lg*16) ^ fsw));
#pragma unroll
        for (int j = 0; j < NTN; ++j) {
            const int nt = nt0 + j, nrow = nt*16 + li;
            const int lsw = (nrow & 7) << 4;
            uint4 b1f[2], b2f[2];
#pragma unroll
            for (int kt = 0; kt < 2; ++kt) {
                b1f[kt] = *(const uint4*)(smem + LN_OFF  + nrow*128 + ((kt*64 + lg*16) ^ lsw));
                b2f[kt] = *(const uint4*)(smem + L2N_OFF + nrow*128 + ((kt*64 + lg*16) ^ lsw));
            }
            f32x4 p1 = {0.f,0.f,0.f,0.f}, p2 = {0.f,0.f,0.f,0.f};
            p1 = __builtin_amdgcn_mfma_f32_16x16x32_bf16(a0[0], ubf(b1f[0]), p1, 0,0,0);
            p1 = __builtin_amdgcn_mfma_f32_16x16x32_bf16(a0[1], ubf(b1f[1]), p1, 0,0,0);
            p2 = __builtin_amdgcn_mfma_f32_16x16x32_bf16(a0[0], ubf(b2f[0]), p2, 0,0,0);
            p2 = __builtin_amdgcn_mfma_f32_16x16x32_bf16(a0[1], ubf(b2f[1]), p2, 0,0,0);
            const int cb = ((mt*16 + lg*4)*2) ^ ((nrow & TSM) << 4);
            unsigned short q0 = f2bf(p1[0]), q1 = f2bf(p1[1]), q2 = f2bf(p1[2]), q3 = f2bf(p1[3]);
            *(uint2*)(Tn1 + nrow*TST + cb) =
                make_uint2(q0 | ((unsigned)q1<<16), q2 | ((unsigned)q3<<16));
            q0 = f2bf(p2[0]); q1 = f2bf(p2[1]); q2 = f2bf(p2[2]); q3 = f2bf(p2[3]);
            *(uint2*)(Tn2 + nrow*TST + cb) =
                make_uint2(q0 | ((unsigned)q1<<16), q2 | ((unsigned)q3<<16));
        }
    }
    __syncthreads();

    // ---------------- weight: wave (node-tile mw, fout-half foh)
    const int mw = w & 3, foh = w >> 2;
    f32x4 acc[NFO];
#pragma unroll
    for (int f = 0; f < NFO; ++f) acc[f] = (f32x4){0.f,0.f,0.f,0.f};
    {
        const int arow = mw*16 + li;
        const int asw  = (arow & TSM) << 4;
#pragma unroll
        for (int t3 = 0; t3 < 3; ++t3) {
            const char* src = (t3 == 0) ? H : (t3 == 1) ? Tn1 : Tn2;
#pragma unroll
            for (int k = 0; k < NKT; ++k) {
                bf16x8 ta = *(const bf16x8*)(src + arow*TST + ((k*64 + lg*16) ^ asw));
#pragma unroll
                for (int f = 0; f < NFO; ++f) {
                    uint4 wf = Wp[((size_t)(t3*NKT + k)*NNT + foh*NFO + f)*64 + lane];
                    acc[f] = __builtin_amdgcn_mfma_f32_16x16x32_bf16(ta, ubf(wf), acc[f], 0,0,0);
                }
            }
        }
    }
    __syncthreads();

    if (!LAST) {
        // ---------------- epilogue: bias(+ReLU) -> H (scatter b16) + Ht (uint2)
        constexpr int OST = (FOUT == 128) ? 256 : 128;
        constexpr int OSM = (FOUT == 128) ? 15 : 7;
#pragma unroll
        for (int f = 0; f < NFO; ++f) {
            const int fo = (foh*NFO + f)*16 + li;
            const float bv = bias[fo];
            unsigned short q[4];
#pragma unroll
            for (int r = 0; r < 4; ++r) {
                float o = acc[f][r] + bv;
                if (RELU) o = fmaxf(o, 0.f);
                q[r] = f2bf(o);
            }
            const int node0 = mw*16 + lg*4;
#pragma unroll
            for (int r = 0; r < 4; ++r)
                *(unsigned short*)(H + (node0+r)*OST + ((fo*2) ^ (((node0+r) & OSM) << 4))) = q[r];
            *(uint2*)(Ht + fo*128 + ((node0*2) ^ ((fo & 7) << 4))) =
                make_uint2(q[0] | ((unsigned)q[1]<<16), q[2] | ((unsigned)q[3]<<16));
        }
        __syncthreads();
    } else {
        // ---------------- last layer: reduce to per-(node-tile) mean/max partials
        float* pS = (float*)(smem + LN_OFF);          // [4][64]
        float* pM = (float*)(smem + LN_OFF + 1024);   // [4][64]
#pragma unroll
        for (int f = 0; f < NFO; ++f) {
            const int fo = (foh*NFO + f)*16 + li;
            f32x4 v = acc[f];
            float s = v[0] + v[1] + v[2] + v[3];
            float m = fmaxf(fmaxf(v[0], v[1]), fmaxf(v[2], v[3]));
            s += __shfl_xor(s, 16); s += __shfl_xor(s, 32);
            m = fmaxf(m, __shfl_xor(m, 16)); m = fmaxf(m, __shfl_xor(m, 32));
            if (lg == 0) { pS[mw*64 + fo] = s; pM[mw*64 + fo] = m; }
        }
        __syncthreads();
    }
}

// ---------------------------------------------------------------------------
// fused: L_hat + L2=2L^2-I operators -> 3 ChebConv layers -> meanmax + FC.
// One block (512 threads, 8 waves) per graph; 80KB LDS -> 2 blocks/CU.
// ---------------------------------------------------------------------------
__global__ __launch_bounds__(512, 4) void fused(
    const float* __restrict__ X,  const float* __restrict__ ew,
    const int* __restrict__ row,  const int* __restrict__ col,
    const uint4* __restrict__ Wp,
    const float* __restrict__ b1, const float* __restrict__ b2,
    const float* __restrict__ b3,
    const float* __restrict__ fcw, const float* __restrict__ fcb,
    float* __restrict__ outp)
{
    __shared__ __align__(16) char smem[LDS_SZ];
    const int g = blockIdx.x, t = threadIdx.x;
    const int w = t >> 6, lane = t & 63, lg = lane >> 4, li = lane & 15;

    // ---- early global loads (hide HBM latency under phase 0)
    const float4* xg = (const float4*)(X + (size_t)g * 4096);
    float4 xv0 = xg[t], xv1 = xg[t + 512];
    const int e0 = g * EPG;
    int er[4], ec[4]; float ev[4];
#pragma unroll
    for (int j = 0; j < 4; ++j) {
        er[j] = row[e0 + t + 512*j] & 63;
        ec[j] = col[e0 + t + 512*j] & 63;
        ev[j] = ew[e0 + t + 512*j];
    }

    float* sA    = (float*)(smem + TN1_OFF);   // [64][64] f32: sA[k][n] = L_hat^T
    float* sdinv = (float*)(smem + TN2_OFF);

    // ---- phase 0a: dense scatter
    for (int i = t; i < 4096; i += 512) sA[i] = 0.f;
    __syncthreads();
#pragma unroll
    for (int j = 0; j < 4; ++j) atomicAdd(&sA[er[j]*64 + ec[j]], ev[j]);
    __syncthreads();

    // ---- 0b: deg = row-sum -> dinv
    {
        const int r = t >> 3, s8 = (t & 7) * 8;
        float p = 0.f;
#pragma unroll
        for (int j = 0; j < 8; ++j) p += sA[r*64 + s8 + j];
        p += __shfl_xor(p, 1); p += __shfl_xor(p, 2); p += __shfl_xor(p, 4);
        if ((t & 7) == 0) sdinv[r] = (p > 0.f) ? rsqrtf(p) : 0.f;
    }
    __syncthreads();

    // ---- 0c: normalize in place: sA[k][n] = -dinv[k]*ew*dinv[n]  (= L^T[k][n])
    for (int i = t; i < 4096; i += 512) {
        const int r = i >> 6, c = i & 63;
        sA[i] = -sA[i] * sdinv[r] * sdinv[c];
    }
    __syncthreads();

    // ---- 0d: pack Ln[n][k] bf16 (L^T frag store) + stage x into H/Ht
    {
        const int n = t >> 3, kq = t & 7;
        unsigned vv[4];
#pragma unroll
        for (int jp = 0; jp < 4; ++jp) {
            unsigned lo = f2bf(sA[(kq*8 + 2*jp    )*64 + n]);
            unsigned hi = f2bf(sA[(kq*8 + 2*jp + 1)*64 + n]);
            vv[jp] = lo | (hi << 16);
        }
        *(uint4*)(smem + LN_OFF + n*128 + ((kq*16) ^ ((n & 7) << 4))) =
            make_uint4(vv[0], vv[1], vv[2], vv[3]);
    }
    {
        char* H  = smem + H_OFF;
        char* Ht = smem + HT_OFF;
#pragma unroll
        for (int half = 0; half < 2; ++half) {
            const int i = t + half*512;
            const float4 v = half ? xv1 : xv0;
            const int node = i >> 4, f0 = (i & 15) * 4;
            unsigned short h[4] = { f2bf(v.x), f2bf(v.y), f2bf(v.z), f2bf(v.w) };
            *(uint2*)(H + node*128 + ((f0*2) ^ ((node & 7) << 4))) =
                make_uint2(h[0] | ((unsigned)h[1]<<16), h[2] | ((unsigned)h[3]<<16));
#pragma unroll
            for (int r = 0; r < 4; ++r)
                *(unsigned short*)(Ht + (f0+r)*128 + ((node*2) ^ (((f0+r) & 7) << 4))) = h[r];
        }
    }
    __syncthreads();

    // ---- 0e: L2^T = 2*(L^T)^2 - I via MFMA; store L2n[n][k] bf16
    {
        const int mt2 = w & 3, nth = w >> 2;
        const int krow = mt2*16 + li;
        bf16x8 a2[2];
#pragma unroll
        for (int kt = 0; kt < 2; ++kt) {
            const float* sp = &sA[krow*64 + kt*32 + lg*8];
            f32x4 s0 = *(const f32x4*)sp;
            f32x4 s1 = *(const f32x4*)(sp + 4);
            unsigned u0 = f2bf(s0[0]) | ((unsigned)f2bf(s0[1]) << 16);
            unsigned u1 = f2bf(s0[2]) | ((unsigned)f2bf(s0[3]) << 16);
            unsigned u2 = f2bf(s1[0]) | ((unsigned)f2bf(s1[1]) << 16);
            unsigned u3 = f2bf(s1[2]) | ((unsigned)f2bf(s1[3]) << 16);
            a2[kt] = ubf(make_uint4(u0, u1, u2, u3));
        }
#pragma unroll
        for (int j = 0; j < 2; ++j) {
            const int nt = nth*2 + j, nrow = nt*16 + li;
            const int lsw = (nrow & 7) << 4;
            uint4 bf0 = *(const uint4*)(smem + LN_OFF + nrow*128 + ((0*64 + lg*16) ^ lsw));
            uint4 bf1 = *(const uint4*)(smem + LN_OFF + nrow*128 + ((1*64 + lg*16) ^ lsw));
            f32x4 p = {0.f,0.f,0.f,0.f};
            p = __builtin_amdgcn_mfma_f32_16x16x32_bf16(a2[0], ubf(bf0), p, 0,0,0);
            p = __builtin_amdgcn_mfma_f32_16x16x32_bf16(a2[1], ubf(bf1), p, 0,0,0);
            unsigned short q[4];
#pragma unroll
            for (int r = 0; r < 4; ++r) {
                const int k = mt2*16 + lg*4 + r;
                float d = 2.f*p[r] - ((k == nrow) ? 1.f : 0.f);
                q[r] = f2bf(d);
            }
            *(uint2*)(smem + L2N_OFF + nrow*128 + (((mt2*16 + lg*4)*2) ^ lsw)) =
                make_uint2(q[0] | ((unsigned)q[1]<<16), q[2] | ((unsigned)q[3]<<16));
        }
    }
    __syncthreads();

    // ---- 3 layers
    layer<64, 128, true,  false>(smem, Wp,                  b1, w, lg, li, lane);
    layer<128, 128, true, false>(smem, Wp + (size_t)48*64,  b2, w, lg, li, lane);
    layer<128, 64, false, true >(smem, Wp + (size_t)144*64, b3, w, lg, li, lane);

    // ---- finalize readout: combine 4 node-tile partials, + bias, FC
    float* pS    = (float*)(smem + LN_OFF);
    float* pM    = (float*)(smem + LN_OFF + 1024);
    float* smean = (float*)(smem + L2N_OFF);
    float* smax  = smean + 64;
    float* part  = smax + 64;
    if (t < 64) {
        float s = pS[t] + pS[64+t] + pS[128+t] + pS[192+t];
        float m = fmaxf(fmaxf(pM[t], pM[64+t]), fmaxf(pM[128+t], pM[192+t]));
        smean[t] = s * (1.f/64.f) + b3[t];
        smax[t]  = m + b3[t];
    }
    __syncthreads();
    if (t < 128) {
        const int j = t & 63, h = t >> 6;
        const float* wv = fcw + (size_t)h*64*64;
        const float* sv = h ? smax : smean;
        float a = 0.f;
        for (int f2 = 0; f2 < 64; ++f2) a += sv[f2] * wv[f2*64 + j];
        part[t] = a;
    }
    __syncthreads();
    if (t < 64) outp[(size_t)g*64 + t] = part[t] + part[64 + t] + fcb[t];
}

// ---------------------------------------------------------------------------
extern "C" void kernel_launch(void* const* d_in, const int* in_sizes, int n_in,
                              void* d_out, int out_size, void* d_ws, size_t ws_size,
                              hipStream_t stream)
{
    const float* x   = (const float*)d_in[0];
    const float* ew  = (const float*)d_in[1];
    const float* W1  = (const float*)d_in[2];
    const float* b1  = (const float*)d_in[3];
    const float* W2  = (const float*)d_in[4];
    const float* b2  = (const float*)d_in[5];
    const float* W3  = (const float*)d_in[6];
    const float* b3  = (const float*)d_in[7];
    const float* fcw = (const float*)d_in[8];
    const float* fcb = (const float*)d_in[9];
    const int*   row = (const int*)d_in[10];
    const int*   col = (const int*)d_in[11];

    uint4* Wp = (uint4*)d_ws;   // 192 frags * 64 lanes * 16B = 192KB

    wpack<<<192, 64, 0, stream>>>(W1, W2, W3, Wp);
    fused<<<NG, 512, 0, stream>>>(x, ew, row, col, Wp,
                                  b1, b2, b3, fcw, fcb, (float*)d_out);
}